// Round 2
// baseline (349.044 us; speedup 1.0000x reference)
//
#include <hip/hip_runtime.h>
#include <math.h>

typedef __attribute__((ext_vector_type(4))) float f4;
typedef __attribute__((ext_vector_type(2))) float f2;

#define NVOX 262144        // 64^3
#define MB_TOT 67108864    // 4*64*NVOX

__device__ __forceinline__ float sigm(float x){ return 1.0f/(1.0f+expf(-x)); }

// ---------------- pass 1: per-(m,c) pooled cell sums + basis-weighted sums ----------------
__global__ __launch_bounds__(256) void k_pass1(const float* __restrict__ x,
                                               float* __restrict__ dsums,
                                               float* __restrict__ xbsums){
  __shared__ float bs[64];
  __shared__ float xb[64];
  int tid = threadIdx.x;
  int mc = blockIdx.x;  // m*64+c
  if (tid < 64){ bs[tid]=0.f; xb[tid]=0.f; }
  __syncthreads();
  const float* xp = x + (size_t)mc * NVOX;
  for (int r = tid; r < 4096; r += 256){   // r = i*64 + j, row over k
    int i = r >> 6, j = r & 63;
    const f4* rowp = reinterpret_cast<const f4*>(xp + (size_t)r * 64);
    float wz0=0.f,wz1=0.f,wz2=0.f,wz3=0.f;
    float ks0=0.f,ks1=0.f,ks2=0.f,ks3=0.f;
#pragma unroll
    for (int ch=0; ch<16; ++ch){
      f4 u = rowp[ch];
#pragma unroll
      for (int e=0; e<4; ++e){
        int k = ch*4+e;
        float f = u[e];
        if (k<16) ks0+=f; else if (k<32) ks1+=f; else if (k<48) ks2+=f; else ks3+=f;
        // hat weights for upsample basis (n_in=4, n_out=64, align_corners=False)
        int lo = (k<8)?0:((k>=56)?3:((k-8)>>4));
        float w = (k<8||k>=56)?0.0f:((k-7.5f)*0.0625f - (float)lo);
        float a0 = f*(1.0f-w), a1 = f*w;
        if (lo==0){ wz0+=a0; wz1+=a1; }
        else if (lo==1){ wz1+=a0; wz2+=a1; }
        else if (lo==2){ wz2+=a0; wz3+=a1; }
        else { wz3+=a0; wz3+=a1; }
      }
    }
    int base = ((i>>4)<<4) + ((j>>4)<<2);
    atomicAdd(&bs[base+0], ks0);
    atomicAdd(&bs[base+1], ks1);
    atomicAdd(&bs[base+2], ks2);
    atomicAdd(&bs[base+3], ks3);
    float ci = fminf(fmaxf((i+0.5f)*0.0625f-0.5f, 0.0f), 3.0f);
    int li=(int)ci; float wi=ci-(float)li; int hiI=li<3?li+1:3;
    float cj = fminf(fmaxf((j+0.5f)*0.0625f-0.5f, 0.0f), 3.0f);
    int lj=(int)cj; float wj=cj-(float)lj; int hj=lj<3?lj+1:3;
    float c00=(1.f-wi)*(1.f-wj), c01=(1.f-wi)*wj, c10=wi*(1.f-wj), c11=wi*wj;
    float wzv0=wz0, wzv1=wz1, wzv2=wz2, wzv3=wz3;
#pragma unroll
    for (int pz=0; pz<4; ++pz){
      float v = (pz==0)?wzv0:((pz==1)?wzv1:((pz==2)?wzv2:wzv3));
      atomicAdd(&xb[li*16+lj*4+pz],  c00*v);
      atomicAdd(&xb[li*16+hj*4+pz],  c01*v);
      atomicAdd(&xb[hiI*16+lj*4+pz], c10*v);
      atomicAdd(&xb[hiI*16+hj*4+pz], c11*v);
    }
  }
  __syncthreads();
  if (tid < 64){
    dsums[(size_t)mc*64+tid]  = bs[tid];
    xbsums[(size_t)mc*64+tid] = xb[tid];
  }
}

// ---------------- pass 2: all tiny MLPs (single block) ----------------
__global__ __launch_bounds__(256) void k_pass2(
    const float* __restrict__ dsums, const float* __restrict__ xbsums,
    const float* __restrict__ wq1, const float* __restrict__ bq1,
    const float* __restrict__ wq2, const float* __restrict__ bq2,
    const float* __restrict__ wa1, const float* __restrict__ ba1,
    const float* __restrict__ wa2, const float* __restrict__ ba2,
    const float* __restrict__ wf,  const float* __restrict__ bfv,
    const float* __restrict__ wg1, const float* __restrict__ bg1,
    const float* __restrict__ wg2, const float* __restrict__ bg2,
    float* __restrict__ wsa, float* __restrict__ wsgate,
    float* __restrict__ wsqw, float* __restrict__ wsinv,
    float* __restrict__ outp)
{
  __shared__ float sGap[256];
  __shared__ float sA[256];
  __shared__ float sCm[256];
  __shared__ float sG[256];
  __shared__ float sGG[16];
  __shared__ float sQw[4];
  int tid = threadIdx.x;
  int m = tid>>6, c = tid&63;
  // gap[m,c]
  {
    float s=0.f;
    const float* dp = dsums + (size_t)tid*64;
    for (int p=0;p<64;++p) s += dp[p];
    sGap[tid] = s * (1.0f/262144.0f);
  }
  // attention MLP on pooled d: thread = (m, p)
  {
    int p = c;
    float h0=0,h1=0,h2=0,h3=0;
    for (int cc=0; cc<64; ++cc){
      float dm = dsums[((size_t)(m*64+cc))*64+p] * (1.0f/4096.0f);
      h0 += dm * wa1[0*64+cc];
      h1 += dm * wa1[1*64+cc];
      h2 += dm * wa1[2*64+cc];
      h3 += dm * wa1[3*64+cc];
    }
    h0 = fmaxf(h0 + ba1[0], 0.f);
    h1 = fmaxf(h1 + ba1[1], 0.f);
    h2 = fmaxf(h2 + ba1[2], 0.f);
    h3 = fmaxf(h3 + ba1[3], 0.f);
    float s = h0*wa2[0] + h1*wa2[1] + h2*wa2[2] + h3*wa2[3] + ba2[0];
    float aa = sigm(s);
    sA[tid] = aa;
    wsa[tid] = aa;
  }
  __syncthreads();
  // quality scores: threads 0..3 (one per modality)
  if (tid < 4){
    int mm = tid;
    float q0=0,q1=0,q2=0,q3=0;
    for (int cc=0; cc<64; ++cc){
      float g = sGap[mm*64+cc];
      q0 += g*wq1[0*64+cc];
      q1 += g*wq1[1*64+cc];
      q2 += g*wq1[2*64+cc];
      q3 += g*wq1[3*64+cc];
    }
    q0 = fmaxf(q0+bq1[0],0.f); q1 = fmaxf(q1+bq1[1],0.f);
    q2 = fmaxf(q2+bq1[2],0.f); q3 = fmaxf(q3+bq1[3],0.f);
    float s0 = sigm(q0*wq2[0]+q1*wq2[1]+q2*wq2[2]+q3*wq2[3]+bq2[0]);
    float s1 = sigm(q0*wq2[4]+q1*wq2[5]+q2*wq2[6]+q3*wq2[7]+bq2[1]);
    sQw[mm] = 0.5f*(s0+s1);
    outp[MB_TOT + mm]     = s0;  // boundary
    outp[MB_TOT + 4 + mm] = s1;  // semantic
  }
  __syncthreads();
  float qw_m = sQw[m];
  float T = sQw[0]+sQw[1]+sQw[2]+sQw[3];
  float inv_m = 1.0f/(T - qw_m);
  if (tid < 4){ wsqw[tid] = sQw[tid]; wsinv[tid] = 1.0f/(T - sQw[tid]); }
  // mean contrib per (m,c):  qw * mean_v(x * a_up) via basis sums
  {
    const float* xbp = xbsums + (size_t)tid*64;
    float s=0.f;
    for (int p=0;p<64;++p) s += sA[m*64+p]*xbp[p];
    sCm[tid] = qw_m * s * (1.0f/262144.0f);
  }
  __syncthreads();
  // g[m,dd] = mean_v fused
  {
    int dd = c;
    float acc=0.f;
    for (int cc=0; cc<64; ++cc){
      float Sm = sCm[0*64+cc]+sCm[1*64+cc]+sCm[2*64+cc]+sCm[3*64+cc];
      float em = (Sm - sCm[m*64+cc]) * inv_m;
      acc += em * wf[dd*64+cc];
    }
    sG[tid] = acc + bfv[dd];
  }
  __syncthreads();
  if (tid < 16){
    int mm = tid>>2, k = tid&3;
    float acc=0.f;
    for (int dd=0; dd<64; ++dd) acc += sG[mm*64+dd]*wg1[k*64+dd];
    sGG[tid] = fmaxf(acc + bg1[k], 0.f);
  }
  __syncthreads();
  {
    float s = sGG[m*4+0]*wg2[c*4+0] + sGG[m*4+1]*wg2[c*4+1]
            + sGG[m*4+2]*wg2[c*4+2] + sGG[m*4+3]*wg2[c*4+3] + bg2[c];
    wsgate[tid] = sigm(s);
  }
}

// ---------------- pass 3: per-voxel 64x64 matvec + epilogue (32 voxels/block) ----------------
__global__ __launch_bounds__(256) void k_pass3(
    const float* __restrict__ x, const float* __restrict__ wf, const float* __restrict__ bfv,
    const float* __restrict__ wsa, const float* __restrict__ wsgate,
    const float* __restrict__ wsqw, const float* __restrict__ wsinv,
    float* __restrict__ outp)
{
  __shared__ __align__(16) float xt[4][64][32];   // [m][c][v]  32 KB
  __shared__ __align__(16) float wfT[64][64];     // wfT[c][dd] 16 KB
  __shared__ float auq[4][32];
  __shared__ float gateL[4][64];
  __shared__ float aCell[4][64];
  __shared__ float bfL[64];
  __shared__ float A2[4][4];
  __shared__ float invL[4];
  int tid = threadIdx.x;
  int b = blockIdx.x;                 // 8192 blocks
  int i = b >> 7;
  int j = (b >> 1) & 63;
  int z0 = (b & 1) * 32;
  size_t V0 = (size_t)b * 32;
  // wf transpose staging: conflict-free LDS writes, strided (L2-hot) global reads
  for (int t = tid; t < 4096; t += 256){
    int cc = t >> 6, dd = t & 63;
    wfT[cc][dd] = wf[dd*64 + cc];
  }
  for (int t = tid; t < 2048; t += 256){   // x tile: 16B chunks
    int vch = t&7, cc=(t>>3)&63, mm=t>>9;
    *reinterpret_cast<f4*>(&xt[mm][cc][vch*4]) =
        *reinterpret_cast<const f4*>(x + ((size_t)(mm*64+cc))*NVOX + V0 + (size_t)vch*4);
  }
  aCell[tid>>6][tid&63] = wsa[tid];
  gateL[tid>>6][tid&63] = wsgate[tid];
  if (tid < 64) bfL[tid] = bfv[tid];
  if (tid < 4)  invL[tid] = wsinv[tid];
  __syncthreads();
  if (tid < 16){  // collapse x,y axes of a
    int mm = tid>>2, pz = tid&3;
    float ci = fminf(fmaxf((i+0.5f)*0.0625f-0.5f,0.f),3.f);
    int li=(int)ci; float wi=ci-(float)li; int hiI=li<3?li+1:3;
    float cj = fminf(fmaxf((j+0.5f)*0.0625f-0.5f,0.f),3.f);
    int lj=(int)cj; float wj=cj-(float)lj; int hj=lj<3?lj+1:3;
    A2[mm][pz] = (1.f-wi)*((1.f-wj)*aCell[mm][li*16+lj*4+pz] + wj*aCell[mm][li*16+hj*4+pz])
               + wi*((1.f-wj)*aCell[mm][hiI*16+lj*4+pz] + wj*aCell[mm][hiI*16+hj*4+pz]);
  }
  __syncthreads();
  if (tid < 128){
    int mm = tid>>5, zl = tid&31;
    int z = z0 + zl;
    float cz = fminf(fmaxf((z+0.5f)*0.0625f-0.5f,0.f),3.f);
    int lz=(int)cz; float wzf=cz-(float)lz; int hz=lz<3?lz+1:3;
    auq[mm][zl] = ((1.f-wzf)*A2[mm][lz] + wzf*A2[mm][hz]) * wsqw[mm];
  }
  __syncthreads();
  int vg = tid & 15, dg = tid >> 4;
  int v0 = vg*2, dd0 = dg*4;
  float acc[4][4][2];
#pragma unroll
  for (int mm=0;mm<4;++mm)
#pragma unroll
    for (int d=0;d<4;++d){ acc[mm][d][0]=0.f; acc[mm][d][1]=0.f; }
#pragma unroll 4
  for (int cc=0; cc<64; ++cc){
    float xv0[4], xv1[4];
#pragma unroll
    for (int mm=0;mm<4;++mm){
      f2 u = *reinterpret_cast<const f2*>(&xt[mm][cc][v0]);
      xv0[mm] = u.x; xv1[mm] = u.y;
    }
    f4 wvv = *reinterpret_cast<const f4*>(&wfT[cc][dd0]);
#pragma unroll
    for (int mm=0;mm<4;++mm)
#pragma unroll
      for (int d=0; d<4; ++d){
        acc[mm][d][0] += xv0[mm]*wvv[d];
        acc[mm][d][1] += xv1[mm]*wvv[d];
      }
  }
  float wmA[4], wmB[4], invv[4];
#pragma unroll
  for (int mm=0;mm<4;++mm){ wmA[mm]=auq[mm][v0]; wmB[mm]=auq[mm][v0+1]; invv[mm]=wsinv[mm]; }
#pragma unroll
  for (int d=0; d<4; ++d){
    int ddg = dd0 + d;
    float bfvv = bfL[ddg];
    float FS0 = wmA[0]*acc[0][d][0]+wmA[1]*acc[1][d][0]+wmA[2]*acc[2][d][0]+wmA[3]*acc[3][d][0];
    float FS1 = wmB[0]*acc[0][d][1]+wmB[1]*acc[1][d][1]+wmB[2]*acc[2][d][1]+wmB[3]*acc[3][d][1];
#pragma unroll
    for (int mm=0;mm<4;++mm){
      float fu0 = (FS0 - wmA[mm]*acc[mm][d][0])*invv[mm] + bfvv;
      float fu1 = (FS1 - wmB[mm]*acc[mm][d][1])*invv[mm] + bfvv;
      float xr0 = xt[mm][ddg][v0], xr1 = xt[mm][ddg][v0+1];
      float g = gateL[mm][ddg];
      f2 o;
      o.x = xr0 + g*fu0;
      o.y = xr1 + g*fu1;
      *reinterpret_cast<f2*>(&outp[((size_t)(mm*64+ddg))*NVOX + V0 + (size_t)v0]) = o;
    }
  }
}

extern "C" void kernel_launch(void* const* d_in, const int* in_sizes, int n_in,
                              void* d_out, int out_size, void* d_ws, size_t ws_size,
                              hipStream_t stream){
  const float* x   = (const float*)d_in[0];
  const float* wq1 = (const float*)d_in[1];
  const float* bq1 = (const float*)d_in[2];
  const float* wq2 = (const float*)d_in[3];
  const float* bq2 = (const float*)d_in[4];
  const float* wa1 = (const float*)d_in[5];
  const float* ba1 = (const float*)d_in[6];
  const float* wa2 = (const float*)d_in[7];
  const float* ba2 = (const float*)d_in[8];
  const float* wf  = (const float*)d_in[9];
  const float* bfv = (const float*)d_in[10];
  const float* wg1 = (const float*)d_in[11];
  const float* bg1 = (const float*)d_in[12];
  const float* wg2 = (const float*)d_in[13];
  const float* bg2 = (const float*)d_in[14];
  float* outp = (float*)d_out;
  float* w = (float*)d_ws;
  float* dsums  = w;            // 16384 floats
  float* xbsums = w + 16384;    // 16384 floats
  float* wsa    = w + 32768;    // 256
  float* wsgate = w + 33024;    // 256
  float* wsqw   = w + 33280;    // 4
  float* wsinv  = w + 33284;    // 4
  hipLaunchKernelGGL(k_pass1, dim3(256), dim3(256), 0, stream, x, dsums, xbsums);
  hipLaunchKernelGGL(k_pass2, dim3(1), dim3(256), 0, stream, dsums, xbsums,
                     wq1,bq1,wq2,bq2,wa1,ba1,wa2,ba2,wf,bfv,wg1,bg1,wg2,bg2,
                     wsa, wsgate, wsqw, wsinv, outp);
  hipLaunchKernelGGL(k_pass3, dim3(8192), dim3(256), 0, stream, x, wf, bfv,
                     wsa, wsgate, wsqw, wsinv, outp);
}

// Round 3
// 311.988 us; speedup vs baseline: 1.1188x; 1.1188x over previous
//
#include <hip/hip_runtime.h>
#include <math.h>

typedef __attribute__((ext_vector_type(4))) float f4;
typedef __attribute__((ext_vector_type(8))) short s8v;   // bf16x8 MFMA fragment

#define NVOX 262144        // 64^3
#define MB_TOT 67108864    // 4*64*NVOX

__device__ __forceinline__ float sigm(float x){ return 1.0f/(1.0f+expf(-x)); }
__device__ __forceinline__ unsigned short f2b(float f){
  unsigned x = __float_as_uint(f);
  return (unsigned short)((x + 0x7fffu + ((x>>16)&1u)) >> 16);
}

// ---------------- pass 1: per-(m,c) pooled cell sums + basis-weighted sums ----------------
// 256 blocks x 1024 threads; block = one (m,c) plane; 4 row-iterations per thread.
__global__ __launch_bounds__(1024) void k_pass1(const float* __restrict__ x,
                                                float* __restrict__ dsums,
                                                float* __restrict__ xbsums){
  __shared__ float bs[64];
  __shared__ float xb[64];
  int tid = threadIdx.x;
  int mc = blockIdx.x;  // m*64+c
  if (tid < 64){ bs[tid]=0.f; xb[tid]=0.f; }
  __syncthreads();
  const float* xp = x + (size_t)mc * NVOX;
  int lane = tid & 63;
#pragma unroll
  for (int it = 0; it < 4; ++it){
    int r = it*1024 + tid;               // row 0..4095 ; r = i*64 + j
    int i = r >> 6, j = r & 63;
    const f4* rowp = reinterpret_cast<const f4*>(xp + (size_t)r * 64);
    float wz0=0.f,wz1=0.f,wz2=0.f,wz3=0.f;
    float ks0=0.f,ks1=0.f,ks2=0.f,ks3=0.f;
#pragma unroll
    for (int ch=0; ch<16; ++ch){
      f4 u = rowp[ch];
#pragma unroll
      for (int e=0; e<4; ++e){
        int k = ch*4+e;                  // compile-time constant -> weights fold
        float f = u[e];
        if (k<16) ks0+=f; else if (k<32) ks1+=f; else if (k<48) ks2+=f; else ks3+=f;
        int lo = (k<8)?0:((k>=56)?3:((k-8)>>4));
        float w = (k<8||k>=56)?0.0f:((k-7.5f)*0.0625f - (float)lo);
        float a0 = f*(1.0f-w), a1 = f*w;
        if (lo==0){ wz0+=a0; wz1+=a1; }
        else if (lo==1){ wz1+=a0; wz2+=a1; }
        else if (lo==2){ wz2+=a0; wz3+=a1; }
        else { wz3+=a0; wz3+=a1; }
      }
    }
    // bs: 16-lane shuffle reduce (lanes in a 16-group share (i>>4, j>>4))
#pragma unroll
    for (int mk=1; mk<16; mk<<=1){
      ks0 += __shfl_xor(ks0, mk, 16);
      ks1 += __shfl_xor(ks1, mk, 16);
      ks2 += __shfl_xor(ks2, mk, 16);
      ks3 += __shfl_xor(ks3, mk, 16);
    }
    if ((lane & 15) == 0){
      int base = ((i>>4)<<4) + ((j>>4)<<2);
      atomicAdd(&bs[base+0], ks0);
      atomicAdd(&bs[base+1], ks1);
      atomicAdd(&bs[base+2], ks2);
      atomicAdd(&bs[base+3], ks3);
    }
    float ci = fminf(fmaxf((i+0.5f)*0.0625f-0.5f, 0.0f), 3.0f);
    int li=(int)ci; float wi=ci-(float)li; int hiI=li<3?li+1:3;
    float cj = fminf(fmaxf((j+0.5f)*0.0625f-0.5f, 0.0f), 3.0f);
    int lj=(int)cj; float wj=cj-(float)lj; int hj=lj<3?lj+1:3;
    float c00=(1.f-wi)*(1.f-wj), c01=(1.f-wi)*wj, c10=wi*(1.f-wj), c11=wi*wj;
#pragma unroll
    for (int pz=0; pz<4; ++pz){
      float v = (pz==0)?wz0:((pz==1)?wz1:((pz==2)?wz2:wz3));
      atomicAdd(&xb[li*16+lj*4+pz],  c00*v);
      atomicAdd(&xb[li*16+hj*4+pz],  c01*v);
      atomicAdd(&xb[hiI*16+lj*4+pz], c10*v);
      atomicAdd(&xb[hiI*16+hj*4+pz], c11*v);
    }
  }
  __syncthreads();
  if (tid < 64){
    atomicAdd(&dsums[(size_t)mc*64+tid],  bs[tid]);
    atomicAdd(&xbsums[(size_t)mc*64+tid], xb[tid]);
  }
}

// ---------------- pass 2: all tiny MLPs (single block) + wf->bf16 conversion ----------------
__global__ __launch_bounds__(256) void k_pass2(
    const float* __restrict__ dsums, const float* __restrict__ xbsums,
    const float* __restrict__ wq1, const float* __restrict__ bq1,
    const float* __restrict__ wq2, const float* __restrict__ bq2,
    const float* __restrict__ wa1, const float* __restrict__ ba1,
    const float* __restrict__ wa2, const float* __restrict__ ba2,
    const float* __restrict__ wf,  const float* __restrict__ bfv,
    const float* __restrict__ wg1, const float* __restrict__ bg1,
    const float* __restrict__ wg2, const float* __restrict__ bg2,
    float* __restrict__ wsa, float* __restrict__ wsgate,
    float* __restrict__ wsqw, float* __restrict__ wsinv,
    unsigned short* __restrict__ wfb,
    float* __restrict__ outp)
{
  __shared__ float sGap[256];
  __shared__ float sA[256];
  __shared__ float sCm[256];
  __shared__ float sG[256];
  __shared__ float sGG[16];
  __shared__ float sQw[4];
  int tid = threadIdx.x;
  int m = tid>>6, c = tid&63;
  // wf -> bf16 for pass3 MFMA B-operand
  for (int t = tid; t < 4096; t += 256) wfb[t] = f2b(wf[t]);
  // gap[m,c]
  {
    float s=0.f;
    const float* dp = dsums + (size_t)tid*64;
    for (int p=0;p<64;++p) s += dp[p];
    sGap[tid] = s * (1.0f/262144.0f);
  }
  // attention MLP on pooled d: thread = (m, p)
  {
    int p = c;
    float h0=0,h1=0,h2=0,h3=0;
    for (int cc=0; cc<64; ++cc){
      float dm = dsums[((size_t)(m*64+cc))*64+p] * (1.0f/4096.0f);
      h0 += dm * wa1[0*64+cc];
      h1 += dm * wa1[1*64+cc];
      h2 += dm * wa1[2*64+cc];
      h3 += dm * wa1[3*64+cc];
    }
    h0 = fmaxf(h0 + ba1[0], 0.f);
    h1 = fmaxf(h1 + ba1[1], 0.f);
    h2 = fmaxf(h2 + ba1[2], 0.f);
    h3 = fmaxf(h3 + ba1[3], 0.f);
    float s = h0*wa2[0] + h1*wa2[1] + h2*wa2[2] + h3*wa2[3] + ba2[0];
    float aa = sigm(s);
    sA[tid] = aa;
    wsa[tid] = aa;
  }
  __syncthreads();
  if (tid < 4){
    int mm = tid;
    float q0=0,q1=0,q2=0,q3=0;
    for (int cc=0; cc<64; ++cc){
      float g = sGap[mm*64+cc];
      q0 += g*wq1[0*64+cc];
      q1 += g*wq1[1*64+cc];
      q2 += g*wq1[2*64+cc];
      q3 += g*wq1[3*64+cc];
    }
    q0 = fmaxf(q0+bq1[0],0.f); q1 = fmaxf(q1+bq1[1],0.f);
    q2 = fmaxf(q2+bq1[2],0.f); q3 = fmaxf(q3+bq1[3],0.f);
    float s0 = sigm(q0*wq2[0]+q1*wq2[1]+q2*wq2[2]+q3*wq2[3]+bq2[0]);
    float s1 = sigm(q0*wq2[4]+q1*wq2[5]+q2*wq2[6]+q3*wq2[7]+bq2[1]);
    sQw[mm] = 0.5f*(s0+s1);
    outp[MB_TOT + mm]     = s0;  // boundary
    outp[MB_TOT + 4 + mm] = s1;  // semantic
  }
  __syncthreads();
  float qw_m = sQw[m];
  float T = sQw[0]+sQw[1]+sQw[2]+sQw[3];
  float inv_m = 1.0f/(T - qw_m);
  if (tid < 4){ wsqw[tid] = sQw[tid]; wsinv[tid] = 1.0f/(T - sQw[tid]); }
  {
    const float* xbp = xbsums + (size_t)tid*64;
    float s=0.f;
    for (int p=0;p<64;++p) s += sA[m*64+p]*xbp[p];
    sCm[tid] = qw_m * s * (1.0f/262144.0f);
  }
  __syncthreads();
  {
    int dd = c;
    float acc=0.f;
    for (int cc=0; cc<64; ++cc){
      float Sm = sCm[0*64+cc]+sCm[1*64+cc]+sCm[2*64+cc]+sCm[3*64+cc];
      float em = (Sm - sCm[m*64+cc]) * inv_m;
      acc += em * wf[dd*64+cc];
    }
    sG[tid] = acc + bfv[dd];
  }
  __syncthreads();
  if (tid < 16){
    int mm = tid>>2, k = tid&3;
    float acc=0.f;
    for (int dd=0; dd<64; ++dd) acc += sG[mm*64+dd]*wg1[k*64+dd];
    sGG[tid] = fmaxf(acc + bg1[k], 0.f);
  }
  __syncthreads();
  {
    float s = sGG[m*4+0]*wg2[c*4+0] + sGG[m*4+1]*wg2[c*4+1]
            + sGG[m*4+2]*wg2[c*4+2] + sGG[m*4+3]*wg2[c*4+3] + bg2[c];
    wsgate[tid] = sigm(s);
  }
}

// ---------------- pass 3: MFMA 64x64 matvec + epilogue, 64 voxels/block, no big LDS ----------------
__global__ __launch_bounds__(256) void k_pass3(
    const float* __restrict__ x, const unsigned short* __restrict__ wfb,
    const float* __restrict__ bfv,
    const float* __restrict__ wsa, const float* __restrict__ wsgate,
    const float* __restrict__ wsqw, const float* __restrict__ wsinv,
    float* __restrict__ outp)
{
  __shared__ float aCell[4][64];
  __shared__ float gateL[4][64];
  __shared__ __align__(16) float auq[4][64];
  __shared__ float bfL[64];
  __shared__ float A2[4][4];
  int tid = threadIdx.x;
  int b = blockIdx.x;                 // 4096 blocks; tile = full z-row (64 voxels)
  int i = b >> 6, j = b & 63;
  size_t V0 = (size_t)b * 64;
  aCell[tid>>6][tid&63] = wsa[tid];
  gateL[tid>>6][tid&63] = wsgate[tid];
  if (tid < 64) bfL[tid] = bfv[tid];
  __syncthreads();
  if (tid < 16){  // collapse x,y axes of attention grid
    int mm = tid>>2, pz = tid&3;
    float ci = fminf(fmaxf((i+0.5f)*0.0625f-0.5f,0.f),3.f);
    int li=(int)ci; float wi=ci-(float)li; int hiI=li<3?li+1:3;
    float cj = fminf(fmaxf((j+0.5f)*0.0625f-0.5f,0.f),3.f);
    int lj=(int)cj; float wj=cj-(float)lj; int hj=lj<3?lj+1:3;
    A2[mm][pz] = (1.f-wi)*((1.f-wj)*aCell[mm][li*16+lj*4+pz] + wj*aCell[mm][li*16+hj*4+pz])
               + wi*((1.f-wj)*aCell[mm][hiI*16+lj*4+pz] + wj*aCell[mm][hiI*16+hj*4+pz]);
  }
  __syncthreads();
  {
    int mm = tid>>6, z = tid&63;
    float cz = fminf(fmaxf((z+0.5f)*0.0625f-0.5f,0.f),3.f);
    int lz=(int)cz; float wzf=cz-(float)lz; int hz=lz<3?lz+1:3;
    auq[mm][z] = ((1.f-wzf)*A2[mm][lz] + wzf*A2[mm][hz]) * wsqw[mm];
  }
  __syncthreads();

  int lane = tid & 63;
  int wv   = tid >> 6;          // wave id -> 16-voxel slice
  int r    = lane & 15;
  int ks   = lane >> 4;
  int vox16 = wv << 4;

  // B fragments: wf rows, bf16, K-contiguous. bf[t][kk]: dd-tile t, K-step kk.
  s8v bf[4][2];
#pragma unroll
  for (int t=0;t<4;++t)
#pragma unroll
    for (int kk=0;kk<2;++kk)
      bf[t][kk] = *reinterpret_cast<const s8v*>(&wfb[(t*16 + r)*64 + kk*32 + ks*8]);

  f4 acc[4][4];
#pragma unroll
  for (int m=0;m<4;++m)
#pragma unroll
    for (int t=0;t<4;++t) acc[m][t] = f4{0.f,0.f,0.f,0.f};

  const float* xbase = x + V0 + vox16 + r;
#pragma unroll
  for (int m=0;m<4;++m){
    s8v af[2];
#pragma unroll
    for (int kk=0;kk<2;++kk){
      union { s8v v; unsigned short u[8]; } pk;
#pragma unroll
      for (int jj=0;jj<8;++jj){
        int cc = kk*32 + ks*8 + jj;
        pk.u[jj] = f2b(xbase[(size_t)(m*64+cc)*NVOX]);
      }
      af[kk] = pk.v;
    }
#pragma unroll
    for (int t=0;t<4;++t){
      acc[m][t] = __builtin_amdgcn_mfma_f32_16x16x32_bf16(af[0], bf[t][0], acc[m][t], 0,0,0);
      acc[m][t] = __builtin_amdgcn_mfma_f32_16x16x32_bf16(af[1], bf[t][1], acc[m][t], 0,0,0);
    }
  }

  // epilogue: lane holds F[dd = 16t + r][vox = vox16 + 4*ks + q], q=0..3
  f4 aq[4];
  float invv[4];
#pragma unroll
  for (int m=0;m<4;++m){
    aq[m]  = *reinterpret_cast<const f4*>(&auq[m][vox16 + 4*ks]);
    invv[m] = wsinv[m];
  }
#pragma unroll
  for (int t=0;t<4;++t){
    int dd = t*16 + r;
    float bfvv = bfL[dd];
    f4 FS = f4{0.f,0.f,0.f,0.f};
#pragma unroll
    for (int m=0;m<4;++m)
#pragma unroll
      for (int q=0;q<4;++q) FS[q] += aq[m][q]*acc[m][t][q];
#pragma unroll
    for (int m=0;m<4;++m){
      size_t off = (size_t)(m*64+dd)*NVOX + V0 + vox16 + 4*ks;
      f4 xv = *reinterpret_cast<const f4*>(x + off);
      float g = gateL[m][dd];
      f4 o;
#pragma unroll
      for (int q=0;q<4;++q){
        float fu = (FS[q] - aq[m][q]*acc[m][t][q])*invv[m] + bfvv;
        o[q] = xv[q] + g*fu;
      }
      *reinterpret_cast<f4*>(outp + off) = o;
    }
  }
}

extern "C" void kernel_launch(void* const* d_in, const int* in_sizes, int n_in,
                              void* d_out, int out_size, void* d_ws, size_t ws_size,
                              hipStream_t stream){
  const float* x   = (const float*)d_in[0];
  const float* wq1 = (const float*)d_in[1];
  const float* bq1 = (const float*)d_in[2];
  const float* wq2 = (const float*)d_in[3];
  const float* bq2 = (const float*)d_in[4];
  const float* wa1 = (const float*)d_in[5];
  const float* ba1 = (const float*)d_in[6];
  const float* wa2 = (const float*)d_in[7];
  const float* ba2 = (const float*)d_in[8];
  const float* wf  = (const float*)d_in[9];
  const float* bfv = (const float*)d_in[10];
  const float* wg1 = (const float*)d_in[11];
  const float* bg1 = (const float*)d_in[12];
  const float* wg2 = (const float*)d_in[13];
  const float* bg2 = (const float*)d_in[14];
  float* outp = (float*)d_out;
  float* w = (float*)d_ws;
  float* dsums  = w;            // 16384 floats
  float* xbsums = w + 16384;    // 16384 floats
  float* wsa    = w + 32768;    // 256
  float* wsgate = w + 33024;    // 256
  float* wsqw   = w + 33280;    // 4
  float* wsinv  = w + 33284;    // 4
  unsigned short* wfb = (unsigned short*)(w + 33288);  // 4096 bf16 (16B-aligned offset)
  hipMemsetAsync(dsums, 0, 32768*sizeof(float), stream);
  hipLaunchKernelGGL(k_pass1, dim3(256), dim3(1024), 0, stream, x, dsums, xbsums);
  hipLaunchKernelGGL(k_pass2, dim3(1), dim3(256), 0, stream, dsums, xbsums,
                     wq1,bq1,wq2,bq2,wa1,ba1,wa2,ba2,wf,bfv,wg1,bg1,wg2,bg2,
                     wsa, wsgate, wsqw, wsinv, wfb, outp);
  hipLaunchKernelGGL(k_pass3, dim3(4096), dim3(256), 0, stream, x, wfb, bfv,
                     wsa, wsgate, wsqw, wsinv, outp);
}

// Round 4
// 291.302 us; speedup vs baseline: 1.1982x; 1.0710x over previous
//
#include <hip/hip_runtime.h>
#include <math.h>

typedef __attribute__((ext_vector_type(4))) float f4;
typedef __attribute__((ext_vector_type(8))) short s8v;   // bf16x8 MFMA fragment
typedef __attribute__((ext_vector_type(4))) unsigned int u4v;

#define NVOX 262144        // 64^3
#define MB_TOT 67108864    // 4*64*NVOX

__device__ __forceinline__ float sigm(float x){ return 1.0f/(1.0f+expf(-x)); }
__device__ __forceinline__ unsigned short f2b(float f){
  unsigned x = __float_as_uint(f);
  return (unsigned short)((x + 0x7fffu + ((x>>16)&1u)) >> 16);
}
__device__ __forceinline__ unsigned cvtpk(float lo, float hi){
  unsigned r;
  asm("v_cvt_pk_bf16_f32 %0, %1, %2" : "=v"(r) : "v"(lo), "v"(hi));
  return r;
}

// ---------------- pass 1: atomic-free separable reduction ----------------
// 256 blocks x 1024 threads; block = one (m,c) plane. Row -> z-collapse in regs,
// then j-collapse and i-collapse through LDS. No atomics anywhere.
__global__ __launch_bounds__(1024) void k_pass1(const float* __restrict__ x,
                                                float* __restrict__ dsums,
                                                float* __restrict__ xbsums){
  __shared__ float rowdat[8][1024];   // [ks0..3, wz0..3][row-in-iter]  32 KB
  __shared__ float txb[64][16];       // [i][py*4+pz]
  __shared__ float tbs[64][16];       // [i][jq*4+kq]
  int tid = threadIdx.x;
  int mc = blockIdx.x;  // m*64+c
  const float* xp = x + (size_t)mc * NVOX;
  for (int it = 0; it < 4; ++it){
    int r = it*1024 + tid;               // row = i*64 + j
    const f4* rowp = reinterpret_cast<const f4*>(xp + (size_t)r * 64);
    float ks0=0.f,ks1=0.f,ks2=0.f,ks3=0.f;
    float wz0=0.f,wz1=0.f,wz2=0.f,wz3=0.f;
#pragma unroll
    for (int ch=0; ch<16; ++ch){
      f4 u = rowp[ch];
#pragma unroll
      for (int e=0; e<4; ++e){
        int k = ch*4+e;                  // compile-time -> weights fold to consts
        float f = u[e];
        if (k<16) ks0+=f; else if (k<32) ks1+=f; else if (k<48) ks2+=f; else ks3+=f;
        int lo = (k<8)?0:((k>=56)?3:((k-8)>>4));
        float w = (k<8||k>=56)?0.0f:((k-7.5f)*0.0625f - (float)lo);
        float a0 = f*(1.0f-w), a1 = f*w;
        if (lo==0){ wz0+=a0; wz1+=a1; }
        else if (lo==1){ wz1+=a0; wz2+=a1; }
        else if (lo==2){ wz2+=a0; wz3+=a1; }
        else { wz3+=a0; wz3+=a1; }
      }
    }
    rowdat[0][tid]=ks0; rowdat[1][tid]=ks1; rowdat[2][tid]=ks2; rowdat[3][tid]=ks3;
    rowdat[4][tid]=wz0; rowdat[5][tid]=wz1; rowdat[6][tid]=wz2; rowdat[7][tid]=wz3;
    __syncthreads();
    if (tid < 256){            // xb j-collapse: thread = (i_loc, py, pz)
      int il = tid>>4, py=(tid>>2)&3, pz=tid&3;
      int base = il*64;
      float s=0.f;
      for (int jj=0; jj<64; ++jj){
        int j = (jj + tid) & 63;         // bank stagger
        float cj = fminf(fmaxf((j+0.5f)*0.0625f-0.5f, 0.0f), 3.0f);
        int lj=(int)cj; float wj=cj-(float)lj;
        float w = (py==lj)?(1.f-wj):((py==lj+1)?wj:0.f);
        s += w * rowdat[4+pz][base+j];
      }
      txb[it*16+il][py*4+pz] = s;
    } else if (tid < 512){     // bs j-collapse: thread = (i_loc, jq, kq)
      int u2 = tid-256;
      int il = u2>>4, jq=(u2>>2)&3, kq=u2&3;
      int base = il*64 + jq*16;
      float s=0.f;
      for (int jj=0; jj<16; ++jj) s += rowdat[kq][base + ((jj+u2)&15)];
      tbs[it*16+il][jq*4+kq] = s;
    }
    __syncthreads();
  }
  if (tid < 64){               // xb i-collapse: p = px*16+py*4+pz
    int px = tid>>4, py=(tid>>2)&3, pz=tid&3;
    float s=0.f;
    for (int i=0;i<64;++i){
      float ci = fminf(fmaxf((i+0.5f)*0.0625f-0.5f, 0.0f), 3.0f);
      int li=(int)ci; float wi=ci-(float)li;
      float w = (px==li)?(1.f-wi):((px==li+1)?wi:0.f);
      s += w * txb[i][py*4+pz];
    }
    xbsums[(size_t)mc*64+tid] = s;
  } else if (tid < 128){       // bs i-collapse: p = iq*16+jq*4+kq
    int p = tid-64;
    int iq = p>>4, jq=(p>>2)&3, kq=p&3;
    float s=0.f;
    for (int i=iq*16; i<iq*16+16; ++i) s += tbs[i][jq*4+kq];
    dsums[(size_t)mc*64+p] = s;
  }
}

// ---------------- pass 2: all tiny MLPs (single block) + wf->bf16 conversion ----------------
__global__ __launch_bounds__(256) void k_pass2(
    const float* __restrict__ dsums, const float* __restrict__ xbsums,
    const float* __restrict__ wq1, const float* __restrict__ bq1,
    const float* __restrict__ wq2, const float* __restrict__ bq2,
    const float* __restrict__ wa1, const float* __restrict__ ba1,
    const float* __restrict__ wa2, const float* __restrict__ ba2,
    const float* __restrict__ wf,  const float* __restrict__ bfv,
    const float* __restrict__ wg1, const float* __restrict__ bg1,
    const float* __restrict__ wg2, const float* __restrict__ bg2,
    float* __restrict__ wsa, float* __restrict__ wsgate,
    float* __restrict__ wsqw, float* __restrict__ wsinv,
    unsigned short* __restrict__ wfb,
    float* __restrict__ outp)
{
  __shared__ float sGap[256];
  __shared__ float sA[256];
  __shared__ float sCm[256];
  __shared__ float sG[256];
  __shared__ float sGG[16];
  __shared__ float sQw[4];
  int tid = threadIdx.x;
  int m = tid>>6, c = tid&63;
  for (int t = tid; t < 4096; t += 256) wfb[t] = f2b(wf[t]);
  {
    float s=0.f;
    const float* dp = dsums + (size_t)tid*64;
    for (int p=0;p<64;++p) s += dp[p];
    sGap[tid] = s * (1.0f/262144.0f);
  }
  {
    int p = c;
    float h0=0,h1=0,h2=0,h3=0;
    for (int cc=0; cc<64; ++cc){
      float dm = dsums[((size_t)(m*64+cc))*64+p] * (1.0f/4096.0f);
      h0 += dm * wa1[0*64+cc];
      h1 += dm * wa1[1*64+cc];
      h2 += dm * wa1[2*64+cc];
      h3 += dm * wa1[3*64+cc];
    }
    h0 = fmaxf(h0 + ba1[0], 0.f);
    h1 = fmaxf(h1 + ba1[1], 0.f);
    h2 = fmaxf(h2 + ba1[2], 0.f);
    h3 = fmaxf(h3 + ba1[3], 0.f);
    float s = h0*wa2[0] + h1*wa2[1] + h2*wa2[2] + h3*wa2[3] + ba2[0];
    float aa = sigm(s);
    sA[tid] = aa;
    wsa[tid] = aa;
  }
  __syncthreads();
  if (tid < 4){
    int mm = tid;
    float q0=0,q1=0,q2=0,q3=0;
    for (int cc=0; cc<64; ++cc){
      float g = sGap[mm*64+cc];
      q0 += g*wq1[0*64+cc];
      q1 += g*wq1[1*64+cc];
      q2 += g*wq1[2*64+cc];
      q3 += g*wq1[3*64+cc];
    }
    q0 = fmaxf(q0+bq1[0],0.f); q1 = fmaxf(q1+bq1[1],0.f);
    q2 = fmaxf(q2+bq1[2],0.f); q3 = fmaxf(q3+bq1[3],0.f);
    float s0 = sigm(q0*wq2[0]+q1*wq2[1]+q2*wq2[2]+q3*wq2[3]+bq2[0]);
    float s1 = sigm(q0*wq2[4]+q1*wq2[5]+q2*wq2[6]+q3*wq2[7]+bq2[1]);
    sQw[mm] = 0.5f*(s0+s1);
    outp[MB_TOT + mm]     = s0;  // boundary
    outp[MB_TOT + 4 + mm] = s1;  // semantic
  }
  __syncthreads();
  float qw_m = sQw[m];
  float T = sQw[0]+sQw[1]+sQw[2]+sQw[3];
  float inv_m = 1.0f/(T - qw_m);
  if (tid < 4){ wsqw[tid] = sQw[tid]; wsinv[tid] = 1.0f/(T - sQw[tid]); }
  {
    const float* xbp = xbsums + (size_t)tid*64;
    float s=0.f;
    for (int p=0;p<64;++p) s += sA[m*64+p]*xbp[p];
    sCm[tid] = qw_m * s * (1.0f/262144.0f);
  }
  __syncthreads();
  {
    int dd = c;
    float acc=0.f;
    for (int cc=0; cc<64; ++cc){
      float Sm = sCm[0*64+cc]+sCm[1*64+cc]+sCm[2*64+cc]+sCm[3*64+cc];
      float em = (Sm - sCm[m*64+cc]) * inv_m;
      acc += em * wf[dd*64+cc];
    }
    sG[tid] = acc + bfv[dd];
  }
  __syncthreads();
  if (tid < 16){
    int mm = tid>>2, k = tid&3;
    float acc=0.f;
    for (int dd=0; dd<64; ++dd) acc += sG[mm*64+dd]*wg1[k*64+dd];
    sGG[tid] = fmaxf(acc + bg1[k], 0.f);
  }
  __syncthreads();
  {
    float s = sGG[m*4+0]*wg2[c*4+0] + sGG[m*4+1]*wg2[c*4+1]
            + sGG[m*4+2]*wg2[c*4+2] + sGG[m*4+3]*wg2[c*4+3] + bg2[c];
    wsgate[tid] = sigm(s);
  }
}

// ---------------- pass 3: LDS-staged bf16 MFMA matvec + epilogue, 64 voxels/block ----------------
__global__ __launch_bounds__(256) void k_pass3(
    const float* __restrict__ x, const unsigned short* __restrict__ wfb,
    const float* __restrict__ bfv,
    const float* __restrict__ wsa, const float* __restrict__ wsgate,
    const float* __restrict__ wsqw, const float* __restrict__ wsinv,
    float* __restrict__ outp)
{
  __shared__ unsigned int xt[4][32][68];   // [m][cc/2][vox] bf16-pair; stride-68 pad  34.8 KB
  __shared__ float aCell[4][64];
  __shared__ float gateL[4][64];
  __shared__ __align__(16) float auq[4][64];
  __shared__ float bfL[64];
  __shared__ float A2[4][4];
  int tid = threadIdx.x;
  int b = blockIdx.x;                 // 4096 blocks; tile = full z-row (64 voxels)
  int i = b >> 6, j = b & 63;
  size_t V0 = (size_t)b * 64;
  int m = tid >> 6, cc = tid & 63;

  // --- staging: coalesced f4 loads of my (m,cc) row, pack cc-pairs to bf16 u32 ---
  const f4* src = reinterpret_cast<const f4*>(x + ((size_t)(m*64+cc))*NVOX + V0);
  f4 v[16];
#pragma unroll
  for (int ch=0; ch<16; ++ch) v[ch] = src[ch];
  aCell[m][cc] = wsa[tid];
  gateL[m][cc] = wsgate[tid];
  if (tid < 64) bfL[tid] = bfv[tid];
  int half = cc & 1, cc2 = cc >> 1;
#pragma unroll
  for (int ch=0; ch<16; ++ch){
    f4 mine = v[ch];
    f4 oth;
#pragma unroll
    for (int q=0;q<4;++q) oth[q] = __shfl_xor(mine[q], 1, 64);
    if ((ch>>3) == half){            // even lane stages vox 0..31, odd stages 32..63
      u4v pk;
#pragma unroll
      for (int q=0;q<4;++q)
        pk[q] = half ? cvtpk(oth[q], mine[q]) : cvtpk(mine[q], oth[q]);
      *reinterpret_cast<u4v*>(&xt[m][cc2][ch*4]) = pk;
    }
  }
  __syncthreads();

  if (tid < 16){  // collapse x,y axes of attention grid
    int mm = tid>>2, pz = tid&3;
    float ci = fminf(fmaxf((i+0.5f)*0.0625f-0.5f,0.f),3.f);
    int li=(int)ci; float wi=ci-(float)li; int hiI=li<3?li+1:3;
    float cj = fminf(fmaxf((j+0.5f)*0.0625f-0.5f,0.f),3.f);
    int lj=(int)cj; float wj=cj-(float)lj; int hj=lj<3?lj+1:3;
    A2[mm][pz] = (1.f-wi)*((1.f-wj)*aCell[mm][li*16+lj*4+pz] + wj*aCell[mm][li*16+hj*4+pz])
               + wi*((1.f-wj)*aCell[mm][hiI*16+lj*4+pz] + wj*aCell[mm][hiI*16+hj*4+pz]);
  }
  __syncthreads();
  {
    int mm = tid>>6, z = tid&63;
    float cz = fminf(fmaxf((z+0.5f)*0.0625f-0.5f,0.f),3.f);
    int lz=(int)cz; float wzf=cz-(float)lz; int hz=lz<3?lz+1:3;
    auq[mm][z] = ((1.f-wzf)*A2[mm][lz] + wzf*A2[mm][hz]) * wsqw[mm];
  }
  __syncthreads();

  int lane = tid & 63;
  int wv   = tid >> 6;          // wave id -> 16-voxel slice
  int r    = lane & 15;
  int ks   = lane >> 4;
  int vox16 = wv << 4;

  // B fragments from global (L2-hot, 8 KB total)
  s8v bfr[4][2];
#pragma unroll
  for (int t=0;t<4;++t)
#pragma unroll
    for (int kk=0;kk<2;++kk)
      bfr[t][kk] = *reinterpret_cast<const s8v*>(&wfb[(t*16 + r)*64 + kk*32 + ks*8]);

  f4 acc[4][4];
#pragma unroll
  for (int mm=0;mm<4;++mm)
#pragma unroll
    for (int t=0;t<4;++t) acc[mm][t] = f4{0.f,0.f,0.f,0.f};

#pragma unroll
  for (int mm=0;mm<4;++mm){
    union { unsigned int u[4]; s8v s; } A0, A1;
#pragma unroll
    for (int q=0;q<4;++q){
      A0.u[q] = xt[mm][ks*4+q][vox16+r];        // kk=0: cc = ks*8 + 2q(+1)
      A1.u[q] = xt[mm][16+ks*4+q][vox16+r];     // kk=1: cc = 32 + ks*8 + 2q(+1)
    }
#pragma unroll
    for (int t=0;t<4;++t){
      acc[mm][t] = __builtin_amdgcn_mfma_f32_16x16x32_bf16(A0.s, bfr[t][0], acc[mm][t], 0,0,0);
      acc[mm][t] = __builtin_amdgcn_mfma_f32_16x16x32_bf16(A1.s, bfr[t][1], acc[mm][t], 0,0,0);
    }
  }

  // epilogue: lane holds F[dd = 16t + r][vox = vox16 + 4*ks + q], q=0..3
  f4 aq[4];
  float invv[4];
#pragma unroll
  for (int mm=0;mm<4;++mm){
    aq[mm]  = *reinterpret_cast<const f4*>(&auq[mm][vox16 + 4*ks]);
    invv[mm] = wsinv[mm];
  }
#pragma unroll
  for (int t=0;t<4;++t){
    int dd = t*16 + r;
    float bfvv = bfL[dd];
    f4 FS = f4{0.f,0.f,0.f,0.f};
#pragma unroll
    for (int mm=0;mm<4;++mm)
#pragma unroll
      for (int q=0;q<4;++q) FS[q] += aq[mm][q]*acc[mm][t][q];
#pragma unroll
    for (int mm=0;mm<4;++mm){
      size_t off = (size_t)(mm*64+dd)*NVOX + V0 + vox16 + 4*ks;
      f4 xv = *reinterpret_cast<const f4*>(x + off);
      float g = gateL[mm][dd];
      f4 o;
#pragma unroll
      for (int q=0;q<4;++q){
        float fu = (FS[q] - aq[mm][q]*acc[mm][t][q])*invv[mm] + bfvv;
        o[q] = xv[q] + g*fu;
      }
      *reinterpret_cast<f4*>(outp + off) = o;
    }
  }
}

extern "C" void kernel_launch(void* const* d_in, const int* in_sizes, int n_in,
                              void* d_out, int out_size, void* d_ws, size_t ws_size,
                              hipStream_t stream){
  const float* x   = (const float*)d_in[0];
  const float* wq1 = (const float*)d_in[1];
  const float* bq1 = (const float*)d_in[2];
  const float* wq2 = (const float*)d_in[3];
  const float* bq2 = (const float*)d_in[4];
  const float* wa1 = (const float*)d_in[5];
  const float* ba1 = (const float*)d_in[6];
  const float* wa2 = (const float*)d_in[7];
  const float* ba2 = (const float*)d_in[8];
  const float* wf  = (const float*)d_in[9];
  const float* bfv = (const float*)d_in[10];
  const float* wg1 = (const float*)d_in[11];
  const float* bg1 = (const float*)d_in[12];
  const float* wg2 = (const float*)d_in[13];
  const float* bg2 = (const float*)d_in[14];
  float* outp = (float*)d_out;
  float* w = (float*)d_ws;
  float* dsums  = w;            // 16384 floats
  float* xbsums = w + 16384;    // 16384 floats
  float* wsa    = w + 32768;    // 256
  float* wsgate = w + 33024;    // 256
  float* wsqw   = w + 33280;    // 4
  float* wsinv  = w + 33284;    // 4
  unsigned short* wfb = (unsigned short*)(w + 33288);  // 4096 bf16
  hipLaunchKernelGGL(k_pass1, dim3(256), dim3(1024), 0, stream, x, dsums, xbsums);
  hipLaunchKernelGGL(k_pass2, dim3(1), dim3(256), 0, stream, dsums, xbsums,
                     wq1,bq1,wq2,bq2,wa1,ba1,wa2,ba2,wf,bfv,wg1,bg1,wg2,bg2,
                     wsa, wsgate, wsqw, wsinv, wfb, outp);
  hipLaunchKernelGGL(k_pass3, dim3(4096), dim3(256), 0, stream, x, wfb, bfv,
                     wsa, wsgate, wsqw, wsinv, outp);
}

// Round 5
// 212.802 us; speedup vs baseline: 1.6402x; 1.3689x over previous
//
#include <hip/hip_runtime.h>
#include <math.h>

typedef __attribute__((ext_vector_type(4))) float f4;
typedef __attribute__((ext_vector_type(8))) short s8v;   // bf16x8 MFMA fragment
typedef __attribute__((ext_vector_type(4))) unsigned int u4v;
typedef __attribute__((ext_vector_type(2))) unsigned int u2v;

#define NVOX 262144        // 64^3
#define MB_TOT 67108864    // 4*64*NVOX

__device__ __forceinline__ float sigm(float x){ return 1.0f/(1.0f+expf(-x)); }
__device__ __forceinline__ unsigned short f2b(float f){
  unsigned x = __float_as_uint(f);
  return (unsigned short)((x + 0x7fffu + ((x>>16)&1u)) >> 16);
}
__device__ __forceinline__ unsigned cvtpk(float lo, float hi){
  unsigned r;
  asm("v_cvt_pk_bf16_f32 %0, %1, %2" : "=v"(r) : "v"(lo), "v"(hi));
  return r;
}
__device__ __forceinline__ float bl(unsigned u){ return __uint_as_float(u<<16); }      // low bf16
__device__ __forceinline__ float bh(unsigned u){ return __uint_as_float(u & 0xffff0000u); } // high bf16

// ---------------- pass 1: coalesced loads + butterfly z-collapse ----------------
// 256 blocks x 1024 threads; block = one (m,c) plane.
// lane mapping: chunk = tid&15 (z-range chunk*4..+3), row-quad = tid>>4.
__global__ __launch_bounds__(1024) void k_pass1(const float* __restrict__ x,
                                                float* __restrict__ dsums,
                                                float* __restrict__ xbsums){
  __shared__ float rowdat[8][1024];   // [ks0..3, wz0..3][row-in-round]  32 KB
  __shared__ float txb[64][16];       // [i][py*4+pz]
  __shared__ float tbs[64][16];       // [i][jq*4+kq]
  int tid = threadIdx.x;
  int mc = blockIdx.x;  // m*64+c
  const float* xp = x + (size_t)mc * NVOX;
  int chunk = tid & 15;
  int rbase = tid >> 4;        // 0..63
  // per-thread z-weights (loop-invariant; lo uniform within a chunk)
  float wq0,wq1,wq2,wq3; int lzc;
  {
    int z0 = chunk*4;
    float cz = fminf(fmaxf((z0+0.5f)*0.0625f-0.5f, 0.0f), 3.0f);
    lzc = (int)cz;
    wq0 = cz - (float)lzc;
    cz = fminf(fmaxf((z0+1.5f)*0.0625f-0.5f, 0.0f), 3.0f); wq1 = cz - (float)lzc;
    cz = fminf(fmaxf((z0+2.5f)*0.0625f-0.5f, 0.0f), 3.0f); wq2 = cz - (float)lzc;
    cz = fminf(fmaxf((z0+3.5f)*0.0625f-0.5f, 0.0f), 3.0f); wq3 = cz - (float)lzc;
  }
  int kb = chunk >> 2;
  for (int round=0; round<4; ++round){
#pragma unroll
    for (int itg=0; itg<4; ++itg){
      f4 u[4];
#pragma unroll
      for (int s=0;s<4;++s){
        int it = itg*4+s;
        int row = round*1024 + it*64 + rbase;
        u[s] = *reinterpret_cast<const f4*>(xp + (size_t)row*64 + chunk*4);
      }
#pragma unroll
      for (int s=0;s<4;++s){
        int it = itg*4+s;
        int rir = it*64 + rbase;         // row-in-round
        f4 v = u[s];
        float ksP = (v.x+v.y)+(v.z+v.w);
        float wB = v.x*wq0 + v.y*wq1 + v.z*wq2 + v.w*wq3;
        float wA = ksP - wB;
        // ks: reduce within 4-lane chunk groups (same z16 bucket)
        ksP += __shfl_xor(ksP, 1, 64);
        ksP += __shfl_xor(ksP, 2, 64);
        // wz: deposit into 4 regs, butterfly over 16 lanes
        float w0 = (lzc==0)?wA:0.f;
        float w1 = (lzc==1)?wA:((lzc==0)?wB:0.f);
        float w2 = (lzc==2)?wA:((lzc==1)?wB:0.f);
        float w3 = (lzc==3)?wA:((lzc==2)?wB:0.f);
#pragma unroll
        for (int mk=1; mk<16; mk<<=1){
          w0 += __shfl_xor(w0, mk, 64);
          w1 += __shfl_xor(w1, mk, 64);
          w2 += __shfl_xor(w2, mk, 64);
          w3 += __shfl_xor(w3, mk, 64);
        }
        if ((chunk&3)==0) rowdat[kb][rir] = ksP;
        if (chunk==0) rowdat[4][rir]=w0;
        if (chunk==1) rowdat[5][rir]=w1;
        if (chunk==2) rowdat[6][rir]=w2;
        if (chunk==3) rowdat[7][rir]=w3;
      }
    }
    __syncthreads();
    if (tid < 256){            // xb j-collapse: thread = (i_loc, py, pz)
      int il = tid>>4, py=(tid>>2)&3, pz=tid&3;
      int base = il*64;
      float s=0.f;
      for (int jj=0; jj<64; ++jj){
        int j = (jj + tid) & 63;         // bank stagger
        float cj = fminf(fmaxf((j+0.5f)*0.0625f-0.5f, 0.0f), 3.0f);
        int lj=(int)cj; float wj=cj-(float)lj;
        float w = (py==lj)?(1.f-wj):((py==lj+1)?wj:0.f);
        s += w * rowdat[4+pz][base+j];
      }
      txb[round*16+il][py*4+pz] = s;
    } else if (tid < 512){     // bs j-collapse: thread = (i_loc, jq, kq)
      int u2 = tid-256;
      int il = u2>>4, jq=(u2>>2)&3, kq=u2&3;
      int base = il*64 + jq*16;
      float s=0.f;
      for (int jj=0; jj<16; ++jj) s += rowdat[kq][base + ((jj+u2)&15)];
      tbs[round*16+il][jq*4+kq] = s;
    }
    __syncthreads();
  }
  if (tid < 64){               // xb i-collapse: p = px*16+py*4+pz
    int px = tid>>4, py=(tid>>2)&3, pz=tid&3;
    float s=0.f;
    for (int i=0;i<64;++i){
      float ci = fminf(fmaxf((i+0.5f)*0.0625f-0.5f, 0.0f), 3.0f);
      int li=(int)ci; float wi=ci-(float)li;
      float w = (px==li)?(1.f-wi):((px==li+1)?wi:0.f);
      s += w * txb[i][py*4+pz];
    }
    xbsums[(size_t)mc*64+tid] = s;
  } else if (tid < 128){       // bs i-collapse: p = iq*16+jq*4+kq
    int p = tid-64;
    int iq = p>>4, jq=(p>>2)&3, kq=p&3;
    float s=0.f;
    for (int i=iq*16; i<iq*16+16; ++i) s += tbs[i][jq*4+kq];
    dsums[(size_t)mc*64+p] = s;
  }
}

// ---------------- pass 2: all tiny MLPs (single block) + wf->bf16 conversion ----------------
__global__ __launch_bounds__(256) void k_pass2(
    const float* __restrict__ dsums, const float* __restrict__ xbsums,
    const float* __restrict__ wq1, const float* __restrict__ bq1,
    const float* __restrict__ wq2, const float* __restrict__ bq2,
    const float* __restrict__ wa1, const float* __restrict__ ba1,
    const float* __restrict__ wa2, const float* __restrict__ ba2,
    const float* __restrict__ wf,  const float* __restrict__ bfv,
    const float* __restrict__ wg1, const float* __restrict__ bg1,
    const float* __restrict__ wg2, const float* __restrict__ bg2,
    float* __restrict__ wsa, float* __restrict__ wsgate,
    float* __restrict__ wsqw, float* __restrict__ wsinv,
    unsigned short* __restrict__ wfb,
    float* __restrict__ outp)
{
  __shared__ float sGap[256];
  __shared__ float sA[256];
  __shared__ float sCm[256];
  __shared__ float sG[256];
  __shared__ float sGG[16];
  __shared__ float sQw[4];
  int tid = threadIdx.x;
  int m = tid>>6, c = tid&63;
  for (int t = tid; t < 4096; t += 256) wfb[t] = f2b(wf[t]);
  {
    float s=0.f;
    const float* dp = dsums + (size_t)tid*64;
    for (int p=0;p<64;++p) s += dp[p];
    sGap[tid] = s * (1.0f/262144.0f);
  }
  {
    int p = c;
    float h0=0,h1=0,h2=0,h3=0;
    for (int cc=0; cc<64; ++cc){
      float dm = dsums[((size_t)(m*64+cc))*64+p] * (1.0f/4096.0f);
      h0 += dm * wa1[0*64+cc];
      h1 += dm * wa1[1*64+cc];
      h2 += dm * wa1[2*64+cc];
      h3 += dm * wa1[3*64+cc];
    }
    h0 = fmaxf(h0 + ba1[0], 0.f);
    h1 = fmaxf(h1 + ba1[1], 0.f);
    h2 = fmaxf(h2 + ba1[2], 0.f);
    h3 = fmaxf(h3 + ba1[3], 0.f);
    float s = h0*wa2[0] + h1*wa2[1] + h2*wa2[2] + h3*wa2[3] + ba2[0];
    float aa = sigm(s);
    sA[tid] = aa;
    wsa[tid] = aa;
  }
  __syncthreads();
  if (tid < 4){
    int mm = tid;
    float q0=0,q1=0,q2=0,q3=0;
    for (int cc=0; cc<64; ++cc){
      float g = sGap[mm*64+cc];
      q0 += g*wq1[0*64+cc];
      q1 += g*wq1[1*64+cc];
      q2 += g*wq1[2*64+cc];
      q3 += g*wq1[3*64+cc];
    }
    q0 = fmaxf(q0+bq1[0],0.f); q1 = fmaxf(q1+bq1[1],0.f);
    q2 = fmaxf(q2+bq1[2],0.f); q3 = fmaxf(q3+bq1[3],0.f);
    float s0 = sigm(q0*wq2[0]+q1*wq2[1]+q2*wq2[2]+q3*wq2[3]+bq2[0]);
    float s1 = sigm(q0*wq2[4]+q1*wq2[5]+q2*wq2[6]+q3*wq2[7]+bq2[1]);
    sQw[mm] = 0.5f*(s0+s1);
    outp[MB_TOT + mm]     = s0;  // boundary
    outp[MB_TOT + 4 + mm] = s1;  // semantic
  }
  __syncthreads();
  float qw_m = sQw[m];
  float T = sQw[0]+sQw[1]+sQw[2]+sQw[3];
  float inv_m = 1.0f/(T - qw_m);
  if (tid < 4){ wsqw[tid] = sQw[tid]; wsinv[tid] = 1.0f/(T - sQw[tid]); }
  {
    const float* xbp = xbsums + (size_t)tid*64;
    float s=0.f;
    for (int p=0;p<64;++p) s += sA[m*64+p]*xbp[p];
    sCm[tid] = qw_m * s * (1.0f/262144.0f);
  }
  __syncthreads();
  {
    int dd = c;
    float acc=0.f;
    for (int cc=0; cc<64; ++cc){
      float Sm = sCm[0*64+cc]+sCm[1*64+cc]+sCm[2*64+cc]+sCm[3*64+cc];
      float em = (Sm - sCm[m*64+cc]) * inv_m;
      acc += em * wf[dd*64+cc];
    }
    sG[tid] = acc + bfv[dd];
  }
  __syncthreads();
  if (tid < 16){
    int mm = tid>>2, k = tid&3;
    float acc=0.f;
    for (int dd=0; dd<64; ++dd) acc += sG[mm*64+dd]*wg1[k*64+dd];
    sGG[tid] = fmaxf(acc + bg1[k], 0.f);
  }
  __syncthreads();
  {
    float s = sGG[m*4+0]*wg2[c*4+0] + sGG[m*4+1]*wg2[c*4+1]
            + sGG[m*4+2]*wg2[c*4+2] + sGG[m*4+3]*wg2[c*4+3] + bg2[c];
    wsgate[tid] = sigm(s);
  }
}

// ---------------- pass 3: coalesced staging + MFMA + coalesced transposed store ----------------
__global__ __launch_bounds__(256) void k_pass3(
    const float* __restrict__ x, const unsigned short* __restrict__ wfb,
    const float* __restrict__ bfv,
    const float* __restrict__ wsa, const float* __restrict__ wsgate,
    const float* __restrict__ wsqw, const float* __restrict__ wsinv,
    float* __restrict__ outp)
{
  __shared__ unsigned int xt[4][32][66];     // [m][cc-pair][vox] bf16 pairs   33.8 KB
  __shared__ unsigned int fusedT[64][34];    // [dd][vox-pair] bf16 pairs       8.7 KB
  __shared__ float aCell[4][64];
  __shared__ float gateL[4][64];
  __shared__ __align__(16) float auq[4][64];
  __shared__ float bfL[64];
  __shared__ float A2[4][4];
  int tid = threadIdx.x;
  int b = blockIdx.x;                 // 4096 blocks; tile = full z-row (64 voxels)
  int i = b >> 6, j = b & 63;
  size_t V0 = (size_t)b * 64;
  int w    = tid >> 6;          // wave id; stages modality w; MFMA vox-slice w
  int lane = tid & 63;
  int ks   = lane >> 4;         // 0..3
  int r    = lane & 15;         // 0..15
  int vox16 = w << 4;

  // --- staging: wave w stages modality w; per instruction: 4 rows x 256 B contiguous ---
  const float* xw = x + (size_t)(w*64)*NVOX + V0 + r*4;
  f4 v[16];
#pragma unroll
  for (int rr=0; rr<16; ++rr){
    int cc = ks*16 + rr;
    v[rr] = *reinterpret_cast<const f4*>(xw + (size_t)cc*NVOX);
  }
  aCell[w][lane] = wsa[tid];
  gateL[w][lane] = wsgate[tid];
  if (tid < 64) bfL[tid] = bfv[tid];
#pragma unroll
  for (int rr=0; rr<16; rr+=2){   // cc-pairs are intra-thread: pack + b128 write
    u4v pk;
#pragma unroll
    for (int q=0;q<4;++q) pk[q] = cvtpk(v[rr][q], v[rr+1][q]);
    *reinterpret_cast<u4v*>(&xt[w][ks*8 + (rr>>1)][r*4]) = pk;
  }
  __syncthreads();

  if (tid < 16){  // collapse x,y axes of attention grid
    int mm = tid>>2, pz = tid&3;
    float ci = fminf(fmaxf((i+0.5f)*0.0625f-0.5f,0.f),3.f);
    int li=(int)ci; float wi=ci-(float)li; int hiI=li<3?li+1:3;
    float cj = fminf(fmaxf((j+0.5f)*0.0625f-0.5f,0.f),3.f);
    int lj=(int)cj; float wj=cj-(float)lj; int hj=lj<3?lj+1:3;
    A2[mm][pz] = (1.f-wi)*((1.f-wj)*aCell[mm][li*16+lj*4+pz] + wj*aCell[mm][li*16+hj*4+pz])
               + wi*((1.f-wj)*aCell[mm][hiI*16+lj*4+pz] + wj*aCell[mm][hiI*16+hj*4+pz]);
  }
  __syncthreads();
  {
    int mm = tid>>6, z = tid&63;
    float cz = fminf(fmaxf((z+0.5f)*0.0625f-0.5f,0.f),3.f);
    int lz=(int)cz; float wzf=cz-(float)lz; int hz=lz<3?lz+1:3;
    auq[mm][z] = ((1.f-wzf)*A2[mm][lz] + wzf*A2[mm][hz]) * wsqw[mm];
  }
  __syncthreads();

  // B fragments from global (8 KB, L2-hot)
  s8v bfr[4][2];
#pragma unroll
  for (int t=0;t<4;++t)
#pragma unroll
    for (int kk=0;kk<2;++kk)
      bfr[t][kk] = *reinterpret_cast<const s8v*>(&wfb[(t*16 + r)*64 + kk*32 + ks*8]);

  f4 acc[4][4];
#pragma unroll
  for (int mm=0;mm<4;++mm)
#pragma unroll
    for (int t=0;t<4;++t) acc[mm][t] = f4{0.f,0.f,0.f,0.f};

#pragma unroll
  for (int mm=0;mm<4;++mm){
    union { unsigned int u[4]; s8v s; } A0, A1;
#pragma unroll
    for (int q=0;q<4;++q){
      A0.u[q] = xt[mm][ks*4+q][vox16+r];        // kk=0: cc pairs 0..15
      A1.u[q] = xt[mm][16+ks*4+q][vox16+r];     // kk=1: cc pairs 16..31
    }
#pragma unroll
    for (int t=0;t<4;++t){
      acc[mm][t] = __builtin_amdgcn_mfma_f32_16x16x32_bf16(A0.s, bfr[t][0], acc[mm][t], 0,0,0);
      acc[mm][t] = __builtin_amdgcn_mfma_f32_16x16x32_bf16(A1.s, bfr[t][1], acc[mm][t], 0,0,0);
    }
  }

  // FS[t][q] = sum_m auq_m * F_m  (lane: dd=16t+r, vox=vox16+4ks+q)
  f4 aq[4]; float invv[4];
#pragma unroll
  for (int mm=0;mm<4;++mm){
    aq[mm]  = *reinterpret_cast<const f4*>(&auq[mm][vox16 + 4*ks]);
    invv[mm] = wsinv[mm];
  }
  f4 FS[4];
#pragma unroll
  for (int t=0;t<4;++t){
    FS[t] = f4{0.f,0.f,0.f,0.f};
#pragma unroll
    for (int mm=0;mm<4;++mm)
#pragma unroll
      for (int q=0;q<4;++q) FS[t][q] += aq[mm][q]*acc[mm][t][q];
  }

  int g4 = tid >> 4;           // 0..15 (row group for store phase)
  int r4l = tid & 15;          // vox/4 within row
#pragma unroll
  for (int mm=0;mm<4;++mm){
    // write fused (bf16 vox-pairs) for modality mm
#pragma unroll
    for (int t=0;t<4;++t){
      int dd = t*16 + r;
      float bfvv = bfL[dd];
      float f0 = (FS[t][0] - aq[mm][0]*acc[mm][t][0])*invv[mm] + bfvv;
      float f1 = (FS[t][1] - aq[mm][1]*acc[mm][t][1])*invv[mm] + bfvv;
      float f2 = (FS[t][2] - aq[mm][2]*acc[mm][t][2])*invv[mm] + bfvv;
      float f3 = (FS[t][3] - aq[mm][3]*acc[mm][t][3])*invv[mm] + bfvv;
      u2v pk2;
      pk2.x = cvtpk(f0, f1);
      pk2.y = cvtpk(f2, f3);
      *reinterpret_cast<u2v*>(&fusedT[dd][(vox16 + ks*4)>>1]) = pk2;
    }
    __syncthreads();
    // coalesced store: per instruction 4 rows x 256 B
#pragma unroll
    for (int rr=0; rr<4; ++rr){
      int dd = rr*16 + g4;
      float g = gateL[mm][dd];
      u4v xu = *reinterpret_cast<const u4v*>(&xt[mm][dd>>1][r4l*4]);
      u2v fu = *reinterpret_cast<const u2v*>(&fusedT[dd][r4l*2]);
      f4 o;
      float x0 = (dd&1) ? bh(xu[0]) : bl(xu[0]);
      float x1 = (dd&1) ? bh(xu[1]) : bl(xu[1]);
      float x2 = (dd&1) ? bh(xu[2]) : bl(xu[2]);
      float x3 = (dd&1) ? bh(xu[3]) : bl(xu[3]);
      o[0] = x0 + g*bl(fu.x);
      o[1] = x1 + g*bh(fu.x);
      o[2] = x2 + g*bl(fu.y);
      o[3] = x3 + g*bh(fu.y);
      *reinterpret_cast<f4*>(outp + (size_t)(mm*64+dd)*NVOX + V0 + r4l*4) = o;
    }
    __syncthreads();
  }
}

extern "C" void kernel_launch(void* const* d_in, const int* in_sizes, int n_in,
                              void* d_out, int out_size, void* d_ws, size_t ws_size,
                              hipStream_t stream){
  const float* x   = (const float*)d_in[0];
  const float* wq1 = (const float*)d_in[1];
  const float* bq1 = (const float*)d_in[2];
  const float* wq2 = (const float*)d_in[3];
  const float* bq2 = (const float*)d_in[4];
  const float* wa1 = (const float*)d_in[5];
  const float* ba1 = (const float*)d_in[6];
  const float* wa2 = (const float*)d_in[7];
  const float* ba2 = (const float*)d_in[8];
  const float* wf  = (const float*)d_in[9];
  const float* bfv = (const float*)d_in[10];
  const float* wg1 = (const float*)d_in[11];
  const float* bg1 = (const float*)d_in[12];
  const float* wg2 = (const float*)d_in[13];
  const float* bg2 = (const float*)d_in[14];
  float* outp = (float*)d_out;
  float* w = (float*)d_ws;
  float* dsums  = w;            // 16384 floats
  float* xbsums = w + 16384;    // 16384 floats
  float* wsa    = w + 32768;    // 256
  float* wsgate = w + 33024;    // 256
  float* wsqw   = w + 33280;    // 4
  float* wsinv  = w + 33284;    // 4
  unsigned short* wfb = (unsigned short*)(w + 33288);  // 4096 bf16
  hipLaunchKernelGGL(k_pass1, dim3(256), dim3(1024), 0, stream, x, dsums, xbsums);
  hipLaunchKernelGGL(k_pass2, dim3(1), dim3(256), 0, stream, dsums, xbsums,
                     wq1,bq1,wq2,bq2,wa1,ba1,wa2,ba2,wf,bfv,wg1,bg1,wg2,bg2,
                     wsa, wsgate, wsqw, wsinv, wfb, outp);
  hipLaunchKernelGGL(k_pass3, dim3(4096), dim3(256), 0, stream, x, wfb, bfv,
                     wsa, wsgate, wsqw, wsinv, outp);
}